// Round 5
// baseline (76.790 us; speedup 1.0000x reference)
//
#include <hip/hip_runtime.h>
#include <hip/hip_bf16.h>

// Flash-attention forward, causal, B=2 H=16 S=2048 D=64, fp32 in/out.
// Round 5: LDS-free register-fragment design. Each wave owns 32 q-rows and a
// uniform strip-pair {63-p, p} (33 KV tiles); K/V fragments loaded directly
// global->VGPR (L2-resident bf16, pre-converted), double-buffered one tile
// ahead via unroll-2 (static register indexing). No barriers, no LDS in the
// attention kernel. bh->blockIdx.x so each head's 8 blocks share one XCD/L2.

#define S_LEN 2048
#define D_DIM 64
#define NBH 32

typedef __bf16 bf16x8 __attribute__((ext_vector_type(8)));
typedef __bf16 bf16x4 __attribute__((ext_vector_type(4)));
typedef float f32x4 __attribute__((ext_vector_type(4)));

#define QSCALE 0.1803368801111243f   // (1/8) * log2(e)
#define NEG_INF (-1e30f)
#define THRLOG2 11.5f                // defer-max threshold (log2 domain) ~ e^8

__device__ inline float m3(float a, float b, float c) {
    return fmaxf(fmaxf(a, b), c);    // clang fuses to v_max3_f32
}

// ---------------- fused convert kernel ----------------
// K: fp32->bf16 row-major [s][d]. V: transposed to [bh][d][s] with per-64-col
// permutation: dest col c=(kk<<5)|(g<<3)|(b<<2)|i0 holds src j=(kk<<5)|(b<<4)|(g<<2)|i0
// so a PV B-fragment is one contiguous 16B read.
__global__ __launch_bounds__(256)
void conv_fused_kernel(const float* __restrict__ k, const float* __restrict__ v,
                       __bf16* __restrict__ kb, __bf16* __restrict__ vt)
{
    __shared__ __bf16 T[64][72];
    const int bh = blockIdx.y, st = blockIdx.x;
    const int tid = threadIdx.x;
    const size_t base = (size_t)bh * S_LEN * D_DIM + (size_t)st * 64 * D_DIM;
    const float* kh = k + base;
    const float* vh = v + base;
    __bf16* kbh = kb + base;

#pragma unroll
    for (int it = 0; it < 2; ++it) {
        size_t i = ((size_t)tid + it * 256) * 8;
        float4 a = *(const float4*)(kh + i);
        float4 b = *(const float4*)(kh + i + 4);
        bf16x8 o;
        o[0] = (__bf16)a.x; o[1] = (__bf16)a.y; o[2] = (__bf16)a.z; o[3] = (__bf16)a.w;
        o[4] = (__bf16)b.x; o[5] = (__bf16)b.y; o[6] = (__bf16)b.z; o[7] = (__bf16)b.w;
        *(bf16x8*)(kbh + i) = o;
    }

#pragma unroll
    for (int it = 0; it < 4; ++it) {
        int idx = tid + it * 256;          // 64 s-rows x 16 float4
        int s = idx >> 4, c4 = idx & 15;
        float4 f = *(const float4*)(vh + s * D_DIM + c4 * 4);
        T[c4 * 4 + 0][s] = (__bf16)f.x;
        T[c4 * 4 + 1][s] = (__bf16)f.y;
        T[c4 * 4 + 2][s] = (__bf16)f.z;
        T[c4 * 4 + 3][s] = (__bf16)f.w;
    }
    __syncthreads();
    __bf16* vth = vt + (size_t)bh * D_DIM * S_LEN + st * 64;
#pragma unroll
    for (int it = 0; it < 2; ++it) {
        int idx = tid + it * 256;          // 64 d-rows x 8 chunks of 8
        int d = idx >> 3, c8 = idx & 7;
        int kk = c8 >> 2, g = c8 & 3;
        bf16x4 v0 = *(const bf16x4*)&T[d][kk * 32 + 4 * g];        // b=0
        bf16x4 v1 = *(const bf16x4*)&T[d][kk * 32 + 16 + 4 * g];   // b=1
        bf16x8 o;
        o[0] = v0[0]; o[1] = v0[1]; o[2] = v0[2]; o[3] = v0[3];
        o[4] = v1[0]; o[5] = v1[1]; o[6] = v1[2]; o[7] = v1[3];
        *(bf16x8*)(vth + (size_t)d * S_LEN + c8 * 8) = o;
    }
}

// ---------------- attention kernel (register fragments, no LDS) ----------------

#define LOADK(KF, kt_)                                                          \
    {                                                                           \
        _Pragma("unroll") for (int jt = 0; jt < 4; ++jt)                        \
        _Pragma("unroll") for (int kk = 0; kk < 2; ++kk)                        \
            KF[jt * 2 + kk] = *(const bf16x8*)(kh +                             \
                ((size_t)((kt_) * 64 + jt * 16 + l15) << 6) + kk * 32 + lg * 8);\
    }

#define LOADV(VF, kt_)                                                          \
    {                                                                           \
        _Pragma("unroll") for (int dt = 0; dt < 4; ++dt)                        \
        _Pragma("unroll") for (int kk = 0; kk < 2; ++kk)                        \
            VF[dt * 2 + kk] = *(const bf16x8*)(vh +                             \
                (size_t)(dt * 16 + l15) * S_LEN + (kt_) * 64 + kk * 32 + lg * 8);\
    }

// One KV tile: prefetch next tile's K/V into KN/VN, QK^T with KC, online
// softmax (defer-max), PV with VC.
#define TILE(KC, KN, VC, VN, kt_)                                               \
    {                                                                           \
        if ((kt_) + 1 < nt) { LOADK(KN, (kt_) + 1); LOADV(VN, (kt_) + 1); }     \
        f32x4 s[4][2];                                                          \
        _Pragma("unroll") for (int jt = 0; jt < 4; ++jt)                        \
        _Pragma("unroll") for (int qc = 0; qc < 2; ++qc) {                      \
            f32x4 c = {};                                                       \
            c = __builtin_amdgcn_mfma_f32_16x16x32_bf16(KC[jt*2+0], qf[qc][0], c, 0, 0, 0); \
            c = __builtin_amdgcn_mfma_f32_16x16x32_bf16(KC[jt*2+1], qf[qc][1], c, 0, 0, 0); \
            s[jt][qc] = c;                                                      \
        }                                                                       \
        if ((kt_) == nt - 1) {                                                  \
            _Pragma("unroll") for (int qc = 0; qc < 2; ++qc) {                  \
                const int qloc = qbase - (kt_) * 64 + qc * 16 + l15;            \
                _Pragma("unroll") for (int jt = 0; jt < 4; ++jt)                \
                _Pragma("unroll") for (int r = 0; r < 4; ++r)                   \
                    if (jt * 16 + 4 * lg + r > qloc) s[jt][qc][r] = NEG_INF;    \
            }                                                                   \
        }                                                                       \
        float mxl[2];                                                           \
        _Pragma("unroll") for (int qc = 0; qc < 2; ++qc) {                      \
            float t0 = m3(s[0][qc][0], s[0][qc][1], s[0][qc][2]);               \
            float t1 = m3(s[0][qc][3], s[1][qc][0], s[1][qc][1]);               \
            float t2 = m3(s[1][qc][2], s[1][qc][3], s[2][qc][0]);               \
            float t3 = m3(s[2][qc][1], s[2][qc][2], s[2][qc][3]);               \
            float t4 = m3(s[3][qc][0], s[3][qc][1], s[3][qc][2]);               \
            mxl[qc] = m3(m3(t0, t1, t2), m3(t3, t4, s[3][qc][3]), NEG_INF);     \
        }                                                                       \
        if (__any(mxl[0] > m_run[0] + THRLOG2 || mxl[1] > m_run[1] + THRLOG2)) {\
            _Pragma("unroll") for (int qc = 0; qc < 2; ++qc) {                  \
                float mx = fmaxf(mxl[qc], __shfl_xor(mxl[qc], 16));             \
                mx = fmaxf(mx, __shfl_xor(mx, 32));                             \
                const float mt   = fmaxf(m_run[qc], mx);                        \
                const float corr = __builtin_amdgcn_exp2f(m_run[qc] - mt);      \
                l_part[qc] *= corr;                                             \
                m_run[qc]   = mt;                                               \
                float ca[4];                                                    \
                _Pragma("unroll") for (int r = 0; r < 4; ++r)                   \
                    ca[r] = __shfl(corr, 4 * lg + r);                           \
                _Pragma("unroll") for (int dt = 0; dt < 4; ++dt)                \
                _Pragma("unroll") for (int r = 0; r < 4; ++r)                   \
                    acc[dt][qc][r] *= ca[r];                                    \
            }                                                                   \
        }                                                                       \
        bf16x8 pa[2][2];                                                        \
        _Pragma("unroll") for (int qc = 0; qc < 2; ++qc) {                      \
            float ps = 0.0f;                                                    \
            float pe[4][4];                                                     \
            _Pragma("unroll") for (int jt = 0; jt < 4; ++jt)                    \
            _Pragma("unroll") for (int r = 0; r < 4; ++r) {                     \
                float e = __builtin_amdgcn_exp2f(s[jt][qc][r] - m_run[qc]);     \
                pe[jt][r] = e;                                                  \
                ps += e;                                                        \
            }                                                                   \
            l_part[qc] += ps;                                                   \
            _Pragma("unroll") for (int kk = 0; kk < 2; ++kk)                    \
            _Pragma("unroll") for (int i = 0; i < 4; ++i) {                     \
                pa[kk][qc][i]     = (__bf16)pe[2 * kk][i];                      \
                pa[kk][qc][4 + i] = (__bf16)pe[2 * kk + 1][i];                  \
            }                                                                   \
        }                                                                       \
        _Pragma("unroll") for (int dt = 0; dt < 4; ++dt)                        \
        _Pragma("unroll") for (int qc = 0; qc < 2; ++qc)                        \
        _Pragma("unroll") for (int kk = 0; kk < 2; ++kk)                        \
            acc[dt][qc] = __builtin_amdgcn_mfma_f32_16x16x32_bf16(              \
                pa[kk][qc], VC[dt * 2 + kk], acc[dt][qc], 0, 0, 0);             \
    }

__global__ __launch_bounds__(256)
void attn_fwd_reg(const float* __restrict__ q, const __bf16* __restrict__ kb,
                  const __bf16* __restrict__ vt, float* __restrict__ out)
{
    const int tid  = threadIdx.x;
    const int w    = tid >> 6;     // wave 0..3 (independent; no block sync)
    const int lane = tid & 63;
    const int l15  = lane & 15;
    const int lg   = lane >> 4;

    const int bh = blockIdx.x;             // bh fastest -> same-head blocks share XCD/L2
    const int p  = blockIdx.y * 4 + w;     // pair index 0..31

    const float*  qh = q  + (size_t)bh * S_LEN * D_DIM;
    const __bf16* kh = kb + (size_t)bh * S_LEN * D_DIM;
    const __bf16* vh = vt + (size_t)bh * D_DIM * S_LEN;
    float*        oh = out + (size_t)bh * S_LEN * D_DIM;

    for (int half = 0; half < 2; ++half) {
        const int strip = (half == 0) ? (63 - p) : p;   // heavy strip first
        const int qbase = strip * 32;
        const int nt    = strip / 2 + 1;

        // Q fragments (B operand): col q = qc*16 + l15, k-elems d = kk*32+8*lg+i
        bf16x8 qf[2][2];
#pragma unroll
        for (int qc = 0; qc < 2; ++qc) {
            const float* qp = qh + (size_t)(qbase + qc * 16 + l15) * D_DIM + 8 * lg;
#pragma unroll
            for (int kk = 0; kk < 2; ++kk) {
                float4 a = *(const float4*)(qp + kk * 32);
                float4 b = *(const float4*)(qp + kk * 32 + 4);
                bf16x8 f;
                f[0] = (__bf16)(a.x * QSCALE); f[1] = (__bf16)(a.y * QSCALE);
                f[2] = (__bf16)(a.z * QSCALE); f[3] = (__bf16)(a.w * QSCALE);
                f[4] = (__bf16)(b.x * QSCALE); f[5] = (__bf16)(b.y * QSCALE);
                f[6] = (__bf16)(b.z * QSCALE); f[7] = (__bf16)(b.w * QSCALE);
                qf[qc][kk] = f;
            }
        }

        f32x4 acc[4][2];
#pragma unroll
        for (int dt = 0; dt < 4; ++dt)
#pragma unroll
            for (int qc = 0; qc < 2; ++qc) acc[dt][qc] = (f32x4){0.f, 0.f, 0.f, 0.f};
        float m_run[2]  = {NEG_INF, NEG_INF};
        float l_part[2] = {0.0f, 0.0f};

        bf16x8 kA[8], kB[8], vA[8], vB[8];
        LOADK(kA, 0);
        LOADV(vA, 0);

        int kt = 0;
        for (; kt + 1 < nt; kt += 2) {
            TILE(kA, kB, vA, vB, kt);
            TILE(kB, kA, vB, vA, kt + 1);
        }
        if (kt < nt) TILE(kA, kB, vA, vB, kt);

        // epilogue: reduce l across lane-copies, O = acc * rcp(l)
        float li[2][4];
#pragma unroll
        for (int qc = 0; qc < 2; ++qc) {
            float lt = l_part[qc] + __shfl_xor(l_part[qc], 16);
            lt += __shfl_xor(lt, 32);
#pragma unroll
            for (int r = 0; r < 4; ++r)
                li[qc][r] = __builtin_amdgcn_rcpf(__shfl(lt, 4 * lg + r));
        }
#pragma unroll
        for (int dt = 0; dt < 4; ++dt)
#pragma unroll
            for (int qc = 0; qc < 2; ++qc)
#pragma unroll
                for (int r = 0; r < 4; ++r)
                    oh[(size_t)(qbase + qc * 16 + 4 * lg + r) * D_DIM + dt * 16 + l15] =
                        acc[dt][qc][r] * li[qc][r];
    }
}

// ---------------- fallback (no-ws path) ----------------

#define PAD 72
__global__ __launch_bounds__(256)
void attn_fwd_fallback(const float* __restrict__ q, const float* __restrict__ k,
                       const float* __restrict__ v, float* __restrict__ out)
{
    __shared__ __bf16 Klds[64][PAD];
    __shared__ __bf16 Vt[D_DIM][PAD];
    __shared__ __bf16 Plds[4][16][PAD];

    const int tid  = threadIdx.x;
    const int w    = tid >> 6;
    const int lane = tid & 63;
    const int l15  = lane & 15;
    const int lg   = lane >> 4;

    const int qtile = blockIdx.x;
    const int bh    = blockIdx.y;
    const int qbase = qtile * 64;

    const size_t head_off = (size_t)bh * S_LEN * D_DIM;
    const float* qh = q + head_off;
    const float* kh = k + head_off;
    const float* vh = v + head_off;
    float*       oh = out + head_off;

    bf16x8 qf[2];
    {
        const int qrow = qbase + w * 16 + l15;
        const float* qp = qh + (size_t)qrow * D_DIM + 8 * lg;
#pragma unroll
        for (int c = 0; c < 2; ++c) {
            float4 a = *(const float4*)(qp + c * 32);
            float4 b = *(const float4*)(qp + c * 32 + 4);
            bf16x8 f;
            f[0] = (__bf16)(a.x * 0.125f); f[1] = (__bf16)(a.y * 0.125f);
            f[2] = (__bf16)(a.z * 0.125f); f[3] = (__bf16)(a.w * 0.125f);
            f[4] = (__bf16)(b.x * 0.125f); f[5] = (__bf16)(b.y * 0.125f);
            f[6] = (__bf16)(b.z * 0.125f); f[7] = (__bf16)(b.w * 0.125f);
            qf[c] = f;
        }
    }

    f32x4 acc[4] = {};
    float m_run[4], l_run[4];
#pragma unroll
    for (int r = 0; r < 4; ++r) { m_run[r] = -1e30f; l_run[r] = 0.0f; }

    const int nkv = qtile + 1;
    for (int kt = 0; kt < nkv; ++kt) {
        const int kv0 = kt * 64;
        __syncthreads();
#pragma unroll
        for (int it = 0; it < 4; ++it) {
            int idx = tid + it * 256;
            int row = idx >> 4;
            int c4  = idx & 15;
            float4 kf = *(const float4*)(kh + (size_t)(kv0 + row) * D_DIM + c4 * 4);
            __bf16* kd = &Klds[row][c4 * 4];
            kd[0] = (__bf16)kf.x; kd[1] = (__bf16)kf.y;
            kd[2] = (__bf16)kf.z; kd[3] = (__bf16)kf.w;
            float4 vf = *(const float4*)(vh + (size_t)(kv0 + row) * D_DIM + c4 * 4);
            Vt[c4 * 4 + 0][row] = (__bf16)vf.x;
            Vt[c4 * 4 + 1][row] = (__bf16)vf.y;
            Vt[c4 * 4 + 2][row] = (__bf16)vf.z;
            Vt[c4 * 4 + 3][row] = (__bf16)vf.w;
        }
        __syncthreads();

        f32x4 sfrag[4];
#pragma unroll
        for (int kc = 0; kc < 4; ++kc) {
            bf16x8 kf0 = *(const bf16x8*)&Klds[kc * 16 + l15][8 * lg];
            bf16x8 kf1 = *(const bf16x8*)&Klds[kc * 16 + l15][32 + 8 * lg];
            f32x4 c = {};
            c = __builtin_amdgcn_mfma_f32_16x16x32_bf16(qf[0], kf0, c, 0, 0, 0);
            c = __builtin_amdgcn_mfma_f32_16x16x32_bf16(qf[1], kf1, c, 0, 0, 0);
            sfrag[kc] = c;
        }

        if (kt == qtile) {
#pragma unroll
            for (int kc = 0; kc < 4; ++kc) {
                const int j = kv0 + kc * 16 + l15;
#pragma unroll
                for (int r = 0; r < 4; ++r) {
                    const int qrow = qbase + w * 16 + lg * 4 + r;
                    if (j > qrow) sfrag[kc][r] = -1e30f;
                }
            }
        }

        float mt[4], corr[4], ps[4];
#pragma unroll
        for (int r = 0; r < 4; ++r) {
            float mx = fmaxf(fmaxf(sfrag[0][r], sfrag[1][r]),
                             fmaxf(sfrag[2][r], sfrag[3][r]));
            mx = fmaxf(mx, __shfl_xor(mx, 1));
            mx = fmaxf(mx, __shfl_xor(mx, 2));
            mx = fmaxf(mx, __shfl_xor(mx, 4));
            mx = fmaxf(mx, __shfl_xor(mx, 8));
            mt[r]   = fmaxf(m_run[r], mx);
            corr[r] = __expf(m_run[r] - mt[r]);
            ps[r]   = 0.0f;
        }
#pragma unroll
        for (int kc = 0; kc < 4; ++kc) {
#pragma unroll
            for (int r = 0; r < 4; ++r) {
                float pp = __expf(sfrag[kc][r] - mt[r]);
                ps[r] += pp;
                Plds[w][lg * 4 + r][kc * 16 + l15] = (__bf16)pp;
            }
        }
#pragma unroll
        for (int r = 0; r < 4; ++r) {
            ps[r] += __shfl_xor(ps[r], 1);
            ps[r] += __shfl_xor(ps[r], 2);
            ps[r] += __shfl_xor(ps[r], 4);
            ps[r] += __shfl_xor(ps[r], 8);
            l_run[r] = l_run[r] * corr[r] + ps[r];
            m_run[r] = mt[r];
        }
#pragma unroll
        for (int dt = 0; dt < 4; ++dt)
#pragma unroll
            for (int r = 0; r < 4; ++r)
                acc[dt][r] *= corr[r];

#pragma unroll
        for (int kk = 0; kk < 2; ++kk) {
            bf16x8 pf = *(const bf16x8*)&Plds[w][l15][kk * 32 + 8 * lg];
#pragma unroll
            for (int dt = 0; dt < 4; ++dt) {
                bf16x8 vf = *(const bf16x8*)&Vt[dt * 16 + l15][kk * 32 + 8 * lg];
                acc[dt] = __builtin_amdgcn_mfma_f32_16x16x32_bf16(pf, vf, acc[dt], 0, 0, 0);
            }
        }
    }

#pragma unroll
    for (int dt = 0; dt < 4; ++dt) {
#pragma unroll
        for (int r = 0; r < 4; ++r) {
            const int qrow = qbase + w * 16 + lg * 4 + r;
            oh[(size_t)qrow * D_DIM + dt * 16 + l15] = acc[dt][r] / l_run[r];
        }
    }
}

extern "C" void kernel_launch(void* const* d_in, const int* in_sizes, int n_in,
                              void* d_out, int out_size, void* d_ws, size_t ws_size,
                              hipStream_t stream) {
    const float* q = (const float*)d_in[0];
    const float* k = (const float*)d_in[1];
    const float* v = (const float*)d_in[2];
    float* out = (float*)d_out;

    const size_t kv_elems  = (size_t)NBH * S_LEN * D_DIM;       // 4,194,304
    const size_t ws_needed = kv_elems * 2 * sizeof(__bf16);     // 16 MiB

    if (ws_size >= ws_needed) {
        __bf16* kb = (__bf16*)d_ws;
        __bf16* vt = kb + kv_elems;
        conv_fused_kernel<<<dim3(S_LEN / 64, NBH), dim3(256), 0, stream>>>(k, v, kb, vt);
        attn_fwd_reg<<<dim3(NBH, 8), dim3(256), 0, stream>>>(q, kb, vt, out);
    } else {
        attn_fwd_fallback<<<dim3(S_LEN / 64, NBH), dim3(256), 0, stream>>>(q, k, v, out);
    }
}

// Round 6
// 60.328 us; speedup vs baseline: 1.2729x; 1.2729x over previous
//
#include <hip/hip_runtime.h>
#include <hip/hip_bf16.h>

// Flash-attention forward, causal, B=2 H=16 S=2048 D=64, fp32 in/out.
// Round 6: r4 LDS structure + KV-parity split. Block (pair p, parity h) does
// qtiles {31-p, p}, KV tiles kt%2==h -> uniform 16-17 tiles/block, grid 1024,
// 2-buffer LDS (32KB) -> 4 blocks/CU = 4 waves/SIMD. Partials (unnormalized O,
// per-row m,l in log2 domain) merged by a combine kernel.

#define S_LEN 2048
#define D_DIM 64
#define BQ 64
#define BKV 64
#define NQT (S_LEN / BQ)
#define NBH 32

typedef __bf16 bf16x8 __attribute__((ext_vector_type(8)));
typedef __bf16 bf16x4 __attribute__((ext_vector_type(4)));
typedef float f32x4 __attribute__((ext_vector_type(4)));

#define QSCALE 0.1803368801111243f   // (1/8) * log2(e)
#define NEG_INF (-1e30f)
#define THRLOG2 11.5f                // defer-max threshold (log2 domain) ~ e^8

__device__ inline void glds16(const void* g, void* l) {
    __builtin_amdgcn_global_load_lds(
        (const __attribute__((address_space(1))) unsigned int*)g,
        (__attribute__((address_space(3))) unsigned int*)l, 16, 0, 0);
}

__device__ inline float m3(float a, float b, float c) {
    return fmaxf(fmaxf(a, b), c);    // clang fuses to v_max3_f32
}

// ---------------- fused convert kernel ----------------
// K: fp32->bf16 [s][d]. V: transposed to [bh][d][s] with per-64-col permutation
// (dest col c=(kk<<5)|(g<<3)|(b<<2)|i0 holds src j=(kk<<5)|(b<<4)|(g<<2)|i0) so
// a PV B-fragment is one contiguous 16B read.
__global__ __launch_bounds__(256)
void conv_fused_kernel(const float* __restrict__ k, const float* __restrict__ v,
                       __bf16* __restrict__ kb, __bf16* __restrict__ vt)
{
    __shared__ __bf16 T[64][72];
    const int bh = blockIdx.y, st = blockIdx.x;
    const int tid = threadIdx.x;
    const size_t base = (size_t)bh * S_LEN * D_DIM + (size_t)st * 64 * D_DIM;
    const float* kh = k + base;
    const float* vh = v + base;
    __bf16* kbh = kb + base;

#pragma unroll
    for (int it = 0; it < 2; ++it) {
        size_t i = ((size_t)tid + it * 256) * 8;
        float4 a = *(const float4*)(kh + i);
        float4 b = *(const float4*)(kh + i + 4);
        bf16x8 o;
        o[0] = (__bf16)a.x; o[1] = (__bf16)a.y; o[2] = (__bf16)a.z; o[3] = (__bf16)a.w;
        o[4] = (__bf16)b.x; o[5] = (__bf16)b.y; o[6] = (__bf16)b.z; o[7] = (__bf16)b.w;
        *(bf16x8*)(kbh + i) = o;
    }

#pragma unroll
    for (int it = 0; it < 4; ++it) {
        int idx = tid + it * 256;          // 64 s-rows x 16 float4
        int s = idx >> 4, c4 = idx & 15;
        float4 f = *(const float4*)(vh + s * D_DIM + c4 * 4);
        T[c4 * 4 + 0][s] = (__bf16)f.x;
        T[c4 * 4 + 1][s] = (__bf16)f.y;
        T[c4 * 4 + 2][s] = (__bf16)f.z;
        T[c4 * 4 + 3][s] = (__bf16)f.w;
    }
    __syncthreads();
    __bf16* vth = vt + (size_t)bh * D_DIM * S_LEN + st * 64;
#pragma unroll
    for (int it = 0; it < 2; ++it) {
        int idx = tid + it * 256;          // 64 d-rows x 8 chunks of 8
        int d = idx >> 3, c8 = idx & 7;
        int kk = c8 >> 2, g = c8 & 3;
        bf16x4 v0 = *(const bf16x4*)&T[d][kk * 32 + 4 * g];        // b=0
        bf16x4 v1 = *(const bf16x4*)&T[d][kk * 32 + 16 + 4 * g];   // b=1
        bf16x8 o;
        o[0] = v0[0]; o[1] = v0[1]; o[2] = v0[2]; o[3] = v0[3];
        o[4] = v1[0]; o[5] = v1[1]; o[6] = v1[2]; o[7] = v1[3];
        *(bf16x8*)(vth + (size_t)d * S_LEN + c8 * 8) = o;
    }
}

// ---------------- split attention kernel (partials) ----------------

#define STAGE(kt, buf)                                                          \
    {                                                                           \
        _Pragma("unroll")                                                       \
        for (int u = 0; u < 2; ++u) {                                           \
            glds16(kh + (size_t)((kt) * BKV + row_u[u]) * D_DIM + scol_u[u],    \
                   (__bf16*)&KL[buf][0][0] + (u * 4 + w) * 512);                \
            glds16(vh + (size_t)row_u[u] * S_LEN + (kt) * BKV + scol_u[u],      \
                   (__bf16*)&VL[buf][0][0] + (u * 4 + w) * 512);                \
        }                                                                       \
    }

__global__ __launch_bounds__(256)
void attn_fwd_split(const float* __restrict__ q, const __bf16* __restrict__ kb,
                    const __bf16* __restrict__ vt, float* __restrict__ opart,
                    float* __restrict__ ml)
{
    __shared__ __bf16 KL[2][64][64];   // [buf][j][d], cols XOR-swizzled by ((j&7)<<3)
    __shared__ __bf16 VL[2][64][64];   // [buf][d][c], permuted cols, swizzled

    const int tid  = threadIdx.x;
    const int w    = tid >> 6;
    const int lane = tid & 63;
    const int l15  = lane & 15;
    const int lg   = lane >> 4;

    const int ph = blockIdx.x;         // 0..31
    const int p  = ph >> 1;            // pair 0..15
    const int h  = ph & 1;             // KV parity
    const int bh = blockIdx.y;

    const float*  qh = q  + (size_t)bh * S_LEN * D_DIM;
    const __bf16* kh = kb + (size_t)bh * S_LEN * D_DIM;
    const __bf16* vh = vt + (size_t)bh * D_DIM * S_LEN;

    // staging decode (chunk c = u*4 + w; LDS elems e = c*512 + lane*8)
    int row_u[2], scol_u[2];
#pragma unroll
    for (int u = 0; u < 2; ++u) {
        int e = (u * 4 + w) * 512 + lane * 8;
        int r = e >> 6, c0 = e & 63;
        row_u[u]  = r;
        scol_u[u] = c0 ^ ((r & 7) << 3);
    }

    for (int half = 0; half < 2; ++half) {
        const int qtile = (half == 0) ? (NQT - 1 - p) : p;
        const int qbase = qtile * BQ;
        const int cnt   = (qtile >= h) ? (((qtile - h) >> 1) + 1) : 0;

        // Q fragment (B operand): l15 = q row, elems d = kk*32 + 8*lg + i
        bf16x8 qf[2];
        {
            const int qrow = qbase + w * 16 + l15;
            const float* qp = qh + (size_t)qrow * D_DIM + 8 * lg;
#pragma unroll
            for (int kk = 0; kk < 2; ++kk) {
                float4 a = *(const float4*)(qp + kk * 32);
                float4 b = *(const float4*)(qp + kk * 32 + 4);
                bf16x8 f;
                f[0] = (__bf16)(a.x * QSCALE); f[1] = (__bf16)(a.y * QSCALE);
                f[2] = (__bf16)(a.z * QSCALE); f[3] = (__bf16)(a.w * QSCALE);
                f[4] = (__bf16)(b.x * QSCALE); f[5] = (__bf16)(b.y * QSCALE);
                f[6] = (__bf16)(b.z * QSCALE); f[7] = (__bf16)(b.w * QSCALE);
                qf[kk] = f;
            }
        }

        f32x4 acc[4] = {};
        float m_run = NEG_INF;
        float l_part = 0.0f;

        if (half == 1) __syncthreads();   // protect LDS reuse across halves
        if (cnt > 0) STAGE(h, 0);

        for (int i = 0; i < cnt; ++i) {
            const int kt  = h + 2 * i;
            const int cur = i & 1;
            asm volatile("s_waitcnt vmcnt(0)" ::: "memory");
            __builtin_amdgcn_s_barrier();
            if (i + 1 < cnt) STAGE(kt + 2, cur ^ 1);

            // swapped QK^T: lane holds S[j][q=l15], j = jt*16 + 4*lg + r
            f32x4 s[4];
            __builtin_amdgcn_s_setprio(1);
#pragma unroll
            for (int jt = 0; jt < 4; ++jt) {
                const int j  = jt * 16 + l15;
                const int sw = (j & 7) << 3;
                f32x4 c = {};
#pragma unroll
                for (int kk = 0; kk < 2; ++kk) {
                    bf16x8 kf = *(const bf16x8*)&KL[cur][j][(kk * 32 + 8 * lg) ^ sw];
                    c = __builtin_amdgcn_mfma_f32_16x16x32_bf16(kf, qf[kk], c, 0, 0, 0);
                }
                s[jt] = c;
            }
            __builtin_amdgcn_s_setprio(0);

            // causal mask on diagonal tile
            if (kt == qtile) {
                const int qin = w * 16 + l15;
#pragma unroll
                for (int jt = 0; jt < 4; ++jt)
#pragma unroll
                    for (int r = 0; r < 4; ++r)
                        if (jt * 16 + 4 * lg + r > qin) s[jt][r] = NEG_INF;
            }

            // local row max
            float t0 = m3(s[0][0], s[0][1], s[0][2]);
            float t1 = m3(s[0][3], s[1][0], s[1][1]);
            float t2 = m3(s[1][2], s[1][3], s[2][0]);
            float t3 = m3(s[2][1], s[2][2], s[2][3]);
            float t4 = m3(s[3][0], s[3][1], s[3][2]);
            float mxl = m3(m3(t0, t1, t2), m3(t3, t4, s[3][3]), NEG_INF);

            // defer-max: cross-lane reduce + rescale only on material growth
            if (__any(mxl > m_run + THRLOG2)) {
                float mx = fmaxf(mxl, __shfl_xor(mxl, 16));
                mx = fmaxf(mx, __shfl_xor(mx, 32));
                const float mt   = fmaxf(m_run, mx);
                const float corr = __builtin_amdgcn_exp2f(m_run - mt);
                l_part *= corr;
                m_run   = mt;
                float corr_a[4];
#pragma unroll
                for (int r = 0; r < 4; ++r) corr_a[r] = __shfl(corr, 4 * lg + r);
#pragma unroll
                for (int dt = 0; dt < 4; ++dt)
#pragma unroll
                    for (int r = 0; r < 4; ++r) acc[dt][r] *= corr_a[r];
            }

            // P = exp2(s - m), per-lane partial sum, bf16 A-fragments
            float ps = 0.0f;
            float pe[4][4];
#pragma unroll
            for (int jt = 0; jt < 4; ++jt)
#pragma unroll
                for (int r = 0; r < 4; ++r) {
                    float e = __builtin_amdgcn_exp2f(s[jt][r] - m_run);
                    pe[jt][r] = e;
                    ps += e;
                }
            l_part += ps;

            bf16x8 pa[2];
#pragma unroll
            for (int kk = 0; kk < 2; ++kk)
#pragma unroll
                for (int i2 = 0; i2 < 4; ++i2) {
                    pa[kk][i2]     = (__bf16)pe[2 * kk][i2];
                    pa[kk][4 + i2] = (__bf16)pe[2 * kk + 1][i2];
                }

            // PV: single b128 B-fragment (permuted V^T)
            __builtin_amdgcn_s_setprio(1);
#pragma unroll
            for (int dt = 0; dt < 4; ++dt) {
                const int d  = dt * 16 + l15;
                const int sw = (d & 7) << 3;
#pragma unroll
                for (int kk = 0; kk < 2; ++kk) {
                    bf16x8 vb = *(const bf16x8*)&VL[cur][d][(kk * 32 + 8 * lg) ^ sw];
                    acc[dt] = __builtin_amdgcn_mfma_f32_16x16x32_bf16(pa[kk], vb, acc[dt], 0, 0, 0);
                }
            }
            __builtin_amdgcn_s_setprio(0);
        }

        // epilogue: write unnormalized partial + per-row (m, l)
        float l_tot = l_part + __shfl_xor(l_part, 16);
        l_tot += __shfl_xor(l_tot, 32);

        float* op = opart + ((((size_t)bh * NQT + qtile) * 2 + h) << 12);
#pragma unroll
        for (int dt = 0; dt < 4; ++dt)
#pragma unroll
            for (int r = 0; r < 4; ++r)
                op[(w * 16 + 4 * lg + r) * 64 + dt * 16 + l15] = acc[dt][r];

        if (lg == 0) {
            float* mlp = ml + ((((size_t)bh * NQT + qtile) * 2 + h) << 7);
            mlp[w * 16 + l15]      = m_run;
            mlp[64 + w * 16 + l15] = l_tot;
        }
    }
}

// ---------------- combine kernel ----------------

__global__ __launch_bounds__(256)
void combine_kernel(const float* __restrict__ opart, const float* __restrict__ ml,
                    float* __restrict__ out)
{
    const int qt  = blockIdx.x;
    const int bh  = blockIdx.y;
    const int tid = threadIdx.x;
    const int row = tid >> 2;          // 0..63
    const int c16 = (tid & 3) * 16;    // col base

    const float* ml0 = ml + ((((size_t)bh * NQT + qt) * 2) << 7);
    const float* ml1 = ml0 + 128;
    const float m0 = ml0[row], l0 = ml0[64 + row];
    const float m1 = ml1[row], l1 = ml1[64 + row];
    const float M  = fmaxf(m0, m1);
    const float w0 = __builtin_amdgcn_exp2f(m0 - M);
    const float w1 = __builtin_amdgcn_exp2f(m1 - M);
    const float li = __builtin_amdgcn_rcpf(w0 * l0 + w1 * l1);

    const float* o0 = opart + ((((size_t)bh * NQT + qt) * 2) << 12) + row * 64 + c16;
    const float* o1 = o0 + 4096;
    float* oh = out + ((size_t)bh * S_LEN + qt * 64 + row) * D_DIM + c16;
#pragma unroll
    for (int c = 0; c < 4; ++c) {
        float4 a = ((const float4*)o0)[c];
        float4 b = ((const float4*)o1)[c];
        float4 o;
        o.x = (a.x * w0 + b.x * w1) * li;
        o.y = (a.y * w0 + b.y * w1) * li;
        o.z = (a.z * w0 + b.z * w1) * li;
        o.w = (a.w * w0 + b.w * w1) * li;
        ((float4*)oh)[c] = o;
    }
}

// ---------------- r4 single-pass kernel (mid fallback, ws >= 16MB) ----------------

__global__ __launch_bounds__(256)
void attn_fwd_glds(const float* __restrict__ q, const __bf16* __restrict__ kb,
                   const __bf16* __restrict__ vt, float* __restrict__ out)
{
    __shared__ __bf16 KL[3][64][64];
    __shared__ __bf16 VL[3][64][64];

    const int tid  = threadIdx.x;
    const int w    = tid >> 6;
    const int lane = tid & 63;
    const int l15  = lane & 15;
    const int lg   = lane >> 4;

    const int p  = blockIdx.x;
    const int bh = blockIdx.y;

    const float*  qh = q  + (size_t)bh * S_LEN * D_DIM;
    const __bf16* kh = kb + (size_t)bh * S_LEN * D_DIM;
    const __bf16* vh = vt + (size_t)bh * D_DIM * S_LEN;
    float*        oh = out + (size_t)bh * S_LEN * D_DIM;

    int row_u[2], scol_u[2];
#pragma unroll
    for (int u = 0; u < 2; ++u) {
        int e = (u * 4 + w) * 512 + lane * 8;
        int r = e >> 6, c0 = e & 63;
        row_u[u]  = r;
        scol_u[u] = c0 ^ ((r & 7) << 3);
    }

    for (int half = 0; half < 2; ++half) {
        const int qtile = (half == 0) ? (NQT - 1 - p) : p;
        const int qbase = qtile * BQ;
        const int nt    = qtile + 1;

        bf16x8 qf[2];
        {
            const int qrow = qbase + w * 16 + l15;
            const float* qp = qh + (size_t)qrow * D_DIM + 8 * lg;
#pragma unroll
            for (int kk = 0; kk < 2; ++kk) {
                float4 a = *(const float4*)(qp + kk * 32);
                float4 b = *(const float4*)(qp + kk * 32 + 4);
                bf16x8 f;
                f[0] = (__bf16)(a.x * QSCALE); f[1] = (__bf16)(a.y * QSCALE);
                f[2] = (__bf16)(a.z * QSCALE); f[3] = (__bf16)(a.w * QSCALE);
                f[4] = (__bf16)(b.x * QSCALE); f[5] = (__bf16)(b.y * QSCALE);
                f[6] = (__bf16)(b.z * QSCALE); f[7] = (__bf16)(b.w * QSCALE);
                qf[kk] = f;
            }
        }

        f32x4 acc[4] = {};
        float m_run = NEG_INF;
        float l_part = 0.0f;

        if (half == 1) __syncthreads();
        STAGE(0, 0);
        if (nt > 1) STAGE(1, 1);

        for (int kt = 0; kt < nt; ++kt) {
            const int cur = kt % 3;
            if (kt + 1 < nt) { asm volatile("s_waitcnt vmcnt(4)" ::: "memory"); }
            else             { asm volatile("s_waitcnt vmcnt(0)" ::: "memory"); }
            __builtin_amdgcn_s_barrier();
            if (kt + 2 < nt) STAGE(kt + 2, (kt + 2) % 3);

            f32x4 s[4];
            __builtin_amdgcn_s_setprio(1);
#pragma unroll
            for (int jt = 0; jt < 4; ++jt) {
                const int j  = jt * 16 + l15;
                const int sw = (j & 7) << 3;
                f32x4 c = {};
#pragma unroll
                for (int kk = 0; kk < 2; ++kk) {
                    bf16x8 kf = *(const bf16x8*)&KL[cur][j][(kk * 32 + 8 * lg) ^ sw];
                    c = __builtin_amdgcn_mfma_f32_16x16x32_bf16(kf, qf[kk], c, 0, 0, 0);
                }
                s[jt] = c;
            }
            __builtin_amdgcn_s_setprio(0);

            if (kt == qtile) {
                const int qin = w * 16 + l15;
#pragma unroll
                for (int jt = 0; jt < 4; ++jt)
#pragma unroll
                    for (int r = 0; r < 4; ++r)
                        if (jt * 16 + 4 * lg + r > qin) s[jt][r] = NEG_INF;
            }

            float t0 = m3(s[0][0], s[0][1], s[0][2]);
            float t1 = m3(s[0][3], s[1][0], s[1][1]);
            float t2 = m3(s[1][2], s[1][3], s[2][0]);
            float t3 = m3(s[2][1], s[2][2], s[2][3]);
            float t4 = m3(s[3][0], s[3][1], s[3][2]);
            float mxl = m3(m3(t0, t1, t2), m3(t3, t4, s[3][3]), NEG_INF);

            if (__any(mxl > m_run + THRLOG2)) {
                float mx = fmaxf(mxl, __shfl_xor(mxl, 16));
                mx = fmaxf(mx, __shfl_xor(mx, 32));
                const float mt   = fmaxf(m_run, mx);
                const float corr = __builtin_amdgcn_exp2f(m_run - mt);
                l_part *= corr;
                m_run   = mt;
                float corr_a[4];
#pragma unroll
                for (int r = 0; r < 4; ++r) corr_a[r] = __shfl(corr, 4 * lg + r);
#pragma unroll
                for (int dt = 0; dt < 4; ++dt)
#pragma unroll
                    for (int r = 0; r < 4; ++r) acc[dt][r] *= corr_a[r];
            }

            float ps = 0.0f;
            float pe[4][4];
#pragma unroll
            for (int jt = 0; jt < 4; ++jt)
#pragma unroll
                for (int r = 0; r < 4; ++r) {
                    float e = __builtin_amdgcn_exp2f(s[jt][r] - m_run);
                    pe[jt][r] = e;
                    ps += e;
                }
            l_part += ps;

            bf16x8 pa[2];
#pragma unroll
            for (int kk = 0; kk < 2; ++kk)
#pragma unroll
                for (int i = 0; i < 4; ++i) {
                    pa[kk][i]     = (__bf16)pe[2 * kk][i];
                    pa[kk][4 + i] = (__bf16)pe[2 * kk + 1][i];
                }

            __builtin_amdgcn_s_setprio(1);
#pragma unroll
            for (int dt = 0; dt < 4; ++dt) {
                const int d  = dt * 16 + l15;
                const int sw = (d & 7) << 3;
#pragma unroll
                for (int kk = 0; kk < 2; ++kk) {
                    bf16x8 vb = *(const bf16x8*)&VL[cur][d][(kk * 32 + 8 * lg) ^ sw];
                    acc[dt] = __builtin_amdgcn_mfma_f32_16x16x32_bf16(pa[kk], vb, acc[dt], 0, 0, 0);
                }
            }
            __builtin_amdgcn_s_setprio(0);
        }

        float l_tot = l_part + __shfl_xor(l_part, 16);
        l_tot += __shfl_xor(l_tot, 32);
        float li_a[4];
#pragma unroll
        for (int r = 0; r < 4; ++r)
            li_a[r] = __builtin_amdgcn_rcpf(__shfl(l_tot, 4 * lg + r));
#pragma unroll
        for (int dt = 0; dt < 4; ++dt)
#pragma unroll
            for (int r = 0; r < 4; ++r)
                oh[(size_t)(qbase + w * 16 + 4 * lg + r) * D_DIM + dt * 16 + l15] =
                    acc[dt][r] * li_a[r];
    }
}
#undef STAGE

// ---------------- raw fallback (no-ws path) ----------------

#define PAD 72
__global__ __launch_bounds__(256)
void attn_fwd_fallback(const float* __restrict__ q, const float* __restrict__ k,
                       const float* __restrict__ v, float* __restrict__ out)
{
    __shared__ __bf16 Klds[64][PAD];
    __shared__ __bf16 Vt[D_DIM][PAD];
    __shared__ __bf16 Plds[4][16][PAD];

    const int tid  = threadIdx.x;
    const int w    = tid >> 6;
    const int lane = tid & 63;
    const int l15  = lane & 15;
    const int lg   = lane >> 4;

    const int qtile = blockIdx.x;
    const int bh    = blockIdx.y;
    const int qbase = qtile * 64;

    const size_t head_off = (size_t)bh * S_LEN * D_DIM;
    const float* qh = q + head_off;
    const float* kh = k + head_off;
    const float* vh = v + head_off;
    float*       oh = out + head_off;

    bf16x8 qf[2];
    {
        const int qrow = qbase + w * 16 + l15;
        const float* qp = qh + (size_t)qrow * D_DIM + 8 * lg;
#pragma unroll
        for (int c = 0; c < 2; ++c) {
            float4 a = *(const float4*)(qp + c * 32);
            float4 b = *(const float4*)(qp + c * 32 + 4);
            bf16x8 f;
            f[0] = (__bf16)(a.x * 0.125f); f[1] = (__bf16)(a.y * 0.125f);
            f[2] = (__bf16)(a.z * 0.125f); f[3] = (__bf16)(a.w * 0.125f);
            f[4] = (__bf16)(b.x * 0.125f); f[5] = (__bf16)(b.y * 0.125f);
            f[6] = (__bf16)(b.z * 0.125f); f[7] = (__bf16)(b.w * 0.125f);
            qf[c] = f;
        }
    }

    f32x4 acc[4] = {};
    float m_run[4], l_run[4];
#pragma unroll
    for (int r = 0; r < 4; ++r) { m_run[r] = -1e30f; l_run[r] = 0.0f; }

    const int nkv = qtile + 1;
    for (int kt = 0; kt < nkv; ++kt) {
        const int kv0 = kt * 64;
        __syncthreads();
#pragma unroll
        for (int it = 0; it < 4; ++it) {
            int idx = tid + it * 256;
            int row = idx >> 4;
            int c4  = idx & 15;
            float4 kf = *(const float4*)(kh + (size_t)(kv0 + row) * D_DIM + c4 * 4);
            __bf16* kd = &Klds[row][c4 * 4];
            kd[0] = (__bf16)kf.x; kd[1] = (__bf16)kf.y;
            kd[2] = (__bf16)kf.z; kd[3] = (__bf16)kf.w;
            float4 vf = *(const float4*)(vh + (size_t)(kv0 + row) * D_DIM + c4 * 4);
            Vt[c4 * 4 + 0][row] = (__bf16)vf.x;
            Vt[c4 * 4 + 1][row] = (__bf16)vf.y;
            Vt[c4 * 4 + 2][row] = (__bf16)vf.z;
            Vt[c4 * 4 + 3][row] = (__bf16)vf.w;
        }
        __syncthreads();

        f32x4 sfrag[4];
#pragma unroll
        for (int kc = 0; kc < 4; ++kc) {
            bf16x8 kf0 = *(const bf16x8*)&Klds[kc * 16 + l15][8 * lg];
            bf16x8 kf1 = *(const bf16x8*)&Klds[kc * 16 + l15][32 + 8 * lg];
            f32x4 c = {};
            c = __builtin_amdgcn_mfma_f32_16x16x32_bf16(qf[0], kf0, c, 0, 0, 0);
            c = __builtin_amdgcn_mfma_f32_16x16x32_bf16(qf[1], kf1, c, 0, 0, 0);
            sfrag[kc] = c;
        }

        if (kt == qtile) {
#pragma unroll
            for (int kc = 0; kc < 4; ++kc) {
                const int j = kv0 + kc * 16 + l15;
#pragma unroll
                for (int r = 0; r < 4; ++r) {
                    const int qrow = qbase + w * 16 + lg * 4 + r;
                    if (j > qrow) sfrag[kc][r] = -1e30f;
                }
            }
        }

        float mt[4], corr[4], ps[4];
#pragma unroll
        for (int r = 0; r < 4; ++r) {
            float mx = fmaxf(fmaxf(sfrag[0][r], sfrag[1][r]),
                             fmaxf(sfrag[2][r], sfrag[3][r]));
            mx = fmaxf(mx, __shfl_xor(mx, 1));
            mx = fmaxf(mx, __shfl_xor(mx, 2));
            mx = fmaxf(mx, __shfl_xor(mx, 4));
            mx = fmaxf(mx, __shfl_xor(mx, 8));
            mt[r]   = fmaxf(m_run[r], mx);
            corr[r] = __expf(m_run[r] - mt[r]);
            ps[r]   = 0.0f;
        }
#pragma unroll
        for (int kc = 0; kc < 4; ++kc) {
#pragma unroll
            for (int r = 0; r < 4; ++r) {
                float pp = __expf(sfrag[kc][r] - mt[r]);
                ps[r] += pp;
                Plds[w][lg * 4 + r][kc * 16 + l15] = (__bf16)pp;
            }
        }
#pragma unroll
        for (int r = 0; r < 4; ++r) {
            ps[r] += __shfl_xor(ps[r], 1);
            ps[r] += __shfl_xor(ps[r], 2);
            ps[r] += __shfl_xor(ps[r], 4);
            ps[r] += __shfl_xor(ps[r], 8);
            l_run[r] = l_run[r] * corr[r] + ps[r];
            m_run[r] = mt[r];
        }
#pragma unroll
        for (int dt = 0; dt < 4; ++dt)
#pragma unroll
            for (int r = 0; r < 4; ++r)
                acc[dt][r] *= corr[r];

#pragma unroll
        for (int kk = 0; kk < 2; ++kk) {
            bf16x8 pf = *(const bf16x8*)&Plds[w][l15][kk * 32 + 8 * lg];
#pragma unroll
            for (int dt = 0; dt < 4; ++dt) {
                bf16x8 vf = *(const bf16x8*)&Vt[dt * 16 + l15][kk * 32 + 8 * lg];
                acc[dt] = __builtin_amdgcn_mfma_f32_16x16x32_bf16(pf, vf, acc[dt], 0, 0, 0);
            }
        }
    }

#pragma unroll
    for (int dt = 0; dt < 4; ++dt) {
#pragma unroll
        for (int r = 0; r < 4; ++r) {
            const int qrow = qbase + w * 16 + lg * 4 + r;
            oh[(size_t)qrow * D_DIM + dt * 16 + l15] = acc[dt][r] / l_run[r];
        }
    }
}

extern "C" void kernel_launch(void* const* d_in, const int* in_sizes, int n_in,
                              void* d_out, int out_size, void* d_ws, size_t ws_size,
                              hipStream_t stream) {
    const float* q = (const float*)d_in[0];
    const float* k = (const float*)d_in[1];
    const float* v = (const float*)d_in[2];
    float* out = (float*)d_out;

    const size_t kv_elems   = (size_t)NBH * S_LEN * D_DIM;          // 4,194,304
    const size_t conv_bytes = kv_elems * 2 * sizeof(__bf16);        // 16 MiB
    const size_t op_bytes   = (size_t)NBH * NQT * 2 * 4096 * 4;     // 32 MiB
    const size_t ml_bytes   = (size_t)NBH * NQT * 2 * 128 * 4;      // 1 MiB

    if (ws_size >= conv_bytes + op_bytes + ml_bytes) {
        __bf16* kb = (__bf16*)d_ws;
        __bf16* vt = kb + kv_elems;
        float* opart = (float*)((char*)d_ws + conv_bytes);
        float* ml    = (float*)((char*)d_ws + conv_bytes + op_bytes);
        conv_fused_kernel<<<dim3(S_LEN / 64, NBH), dim3(256), 0, stream>>>(k, v, kb, vt);
        attn_fwd_split<<<dim3(32, NBH), dim3(256), 0, stream>>>(q, kb, vt, opart, ml);
        combine_kernel<<<dim3(NQT, NBH), dim3(256), 0, stream>>>(opart, ml, out);
    } else if (ws_size >= conv_bytes) {
        __bf16* kb = (__bf16*)d_ws;
        __bf16* vt = kb + kv_elems;
        conv_fused_kernel<<<dim3(S_LEN / 64, NBH), dim3(256), 0, stream>>>(k, v, kb, vt);
        attn_fwd_glds<<<dim3(NQT / 2, NBH), dim3(256), 0, stream>>>(q, kb, vt, out);
    } else {
        attn_fwd_fallback<<<dim3(S_LEN / 64, NBH), dim3(256), 0, stream>>>(q, k, v, out);
    }
}